// Round 5
// baseline (514.290 us; speedup 1.0000x reference)
//
#include <hip/hip_runtime.h>
#include <hip/hip_bf16.h>
#include <math.h>

typedef __bf16 bf16x8 __attribute__((ext_vector_type(8)));
typedef float f32x4 __attribute__((ext_vector_type(4)));
typedef float f32x16 __attribute__((ext_vector_type(16)));
typedef unsigned short u16x8 __attribute__((ext_vector_type(8)));
typedef unsigned short u16x4 __attribute__((ext_vector_type(4)));
typedef unsigned int u32x4 __attribute__((ext_vector_type(4)));

#define DEV __device__ __forceinline__

DEV unsigned short f2bf(float f) { __bf16 h = (__bf16)f; return __builtin_bit_cast(unsigned short, h); }
DEV float bf2f(unsigned short u) { __bf16 h = __builtin_bit_cast(__bf16, u); return (float)h; }
DEV unsigned int pk2(float a, float b) {
  return (unsigned int)f2bf(a) | ((unsigned int)f2bf(b) << 16);
}

DEV void async_cp16(const void* g, void* l) {
  __builtin_amdgcn_global_load_lds((const __attribute__((address_space(1))) void*)g,
                                   (__attribute__((address_space(3))) void*)l, 16, 0, 0);
}

// NOTE (rounds 1-3 post-mortem): a 256x256 8-phase gemm (T2-T5 port) was tried and
// abandoned. Invariant failure signature across builtin-MFMA, launch_bounds(512,1),
// asm "+a" AGPR-pinned variants: VGPR_Count 96-100, WRITE_SIZE 327.7 MB/dispatch
// (~260 MB scratch writes), MfmaUtil 17%, 158 us — the 128-float accumulator's home
// stayed in scratch regardless. Do not retry without .s/scratch_size diagnostics.
// NOTE (round 4): attn SQ_LDS_BANK_CONFLICT == 4 per ds_read_b128 exactly, invariant
// after removing all ds_bpermute -> inherent b128 cost (m134: 12cyc vs 8 ideal),
// not a swizzle bug. Attn is dependency/sync-bound, no pipe >45%.

// ---------------- LayerNorm: one block per row, D=1024 ----------------
__global__ __launch_bounds__(256) void ln_kernel(const float* __restrict__ in,
    const float* __restrict__ g, const float* __restrict__ b,
    unsigned short* __restrict__ out)
{
  const int row = blockIdx.x;
  const int tid = threadIdx.x;
  const float4 v = ((const float4*)(in + (size_t)row * 1024))[tid];
  float s  = v.x + v.y + v.z + v.w;
  float sq = v.x*v.x + v.y*v.y + v.z*v.z + v.w*v.w;
  for (int m = 1; m < 64; m <<= 1) { s += __shfl_xor(s, m); sq += __shfl_xor(sq, m); }
  __shared__ float red[8];
  const int wave = tid >> 6;
  if ((tid & 63) == 0) { red[wave] = s; red[4 + wave] = sq; }
  __syncthreads();
  s  = red[0] + red[1] + red[2] + red[3];
  sq = red[4] + red[5] + red[6] + red[7];
  const float mu = s * (1.0f / 1024.0f);
  const float var = sq * (1.0f / 1024.0f) - mu * mu;
  const float rs = rsqrtf(var + 1e-5f);
  const float4 gv = ((const float4*)g)[tid];
  const float4 bv = ((const float4*)b)[tid];
  u16x4 o;
  o[0] = f2bf((v.x - mu) * rs * gv.x + bv.x);
  o[1] = f2bf((v.y - mu) * rs * gv.y + bv.y);
  o[2] = f2bf((v.z - mu) * rs * gv.z + bv.z);
  o[3] = f2bf((v.w - mu) * rs * gv.w + bv.w);
  *(u16x4*)(out + (size_t)row * 1024 + tid * 4) = o;
}

// ------------- Weight transpose + fp32->bf16: out[N][K] = in[K][N] -------------
__global__ __launch_bounds__(256) void wtrans_kernel(const float* __restrict__ in,
    unsigned short* __restrict__ out, int K, int N)
{
  __shared__ float tile[32][33];
  const int n0 = blockIdx.x * 32, k0 = blockIdx.y * 32;
  const int r = threadIdx.x >> 5, c = threadIdx.x & 31;
  for (int p = 0; p < 4; ++p)
    tile[r + p * 8][c] = in[(size_t)(k0 + r + p * 8) * N + n0 + c];
  __syncthreads();
  for (int p = 0; p < 4; ++p)
    out[(size_t)(n0 + r + p * 8) * K + k0 + c] = f2bf(tile[c][r + p * 8]);
}

// ------------- bf16 GEMM, BK=64: C[M,N] = A[M,K] * Bt[N,K]^T + epilogue -------------
enum { EPI_QKV = 0, EPI_ATTNO = 1, EPI_GELU = 2, EPI_FINAL = 3 };

template <int EPI>
__global__ __launch_bounds__(256, 3) void gemm_bt(
    const unsigned short* __restrict__ A,
    const unsigned short* __restrict__ Bt,
    const float* __restrict__ bias,
    const float* __restrict__ resid,
    void* __restrict__ out,
    int M, int N, int K,
    const float* __restrict__ rc, const float* __restrict__ rsn,
    unsigned short* __restrict__ vout)
{
  __shared__ unsigned short lA[8192] __attribute__((aligned(16)));  // 128x64 bf16, swizzled slots
  __shared__ unsigned short lB[8192] __attribute__((aligned(16)));
  const int tid = threadIdx.x;
  const int lane = tid & 63, wave = tid >> 6;
  const int l15 = lane & 15, quad = lane >> 4;
  const int bm = blockIdx.x * 128, bn = blockIdx.y * 128;   // XCD-aware ordering
  const int wm = (wave & 1) * 64, wn = (wave >> 1) * 64;

  const unsigned short* ga[4]; const unsigned short* gb[4];
  unsigned short* la_dst[4]; unsigned short* lb_dst[4];
  for (int it = 0; it < 4; ++it) {
    const int s = it * 256 + tid;
    const int row = s >> 3;
    const int ch = (s & 7) ^ (row & 7);
    ga[it] = A  + (size_t)(bm + row) * K + ch * 8;
    gb[it] = Bt + (size_t)(bn + row) * K + ch * 8;
    const int base = (it * 256 + wave * 64) * 8;   // wave-uniform LDS base (ushort units)
    la_dst[it] = lA + base;
    lb_dst[it] = lB + base;
  }
  int offA[2][4], offB[2][4];
  for (int ks = 0; ks < 2; ++ks)
    for (int i = 0; i < 4; ++i) {
      int row = wm + i * 16 + l15;
      offA[ks][i] = (row * 8 + ((ks * 4 + quad) ^ (row & 7))) * 8;
      row = wn + i * 16 + l15;
      offB[ks][i] = (row * 8 + ((ks * 4 + quad) ^ (row & 7))) * 8;
    }

  f32x4 acc[4][4];
  for (int i = 0; i < 4; ++i)
    for (int j = 0; j < 4; ++j)
      acc[i][j] = f32x4{0.f, 0.f, 0.f, 0.f};

  for (int k0 = 0; k0 < K; k0 += 64) {
    for (int it = 0; it < 4; ++it) async_cp16(ga[it], la_dst[it]);
    for (int it = 0; it < 4; ++it) async_cp16(gb[it], lb_dst[it]);
    for (int it = 0; it < 4; ++it) { ga[it] += 64; gb[it] += 64; }
    __syncthreads();
    for (int ks = 0; ks < 2; ++ks) {
      bf16x8 af[4], bfr[4];
      for (int i = 0; i < 4; ++i) af[i]  = *(const bf16x8*)(lA + offA[ks][i]);
      for (int j = 0; j < 4; ++j) bfr[j] = *(const bf16x8*)(lB + offB[ks][j]);
      for (int i = 0; i < 4; ++i)
        for (int j = 0; j < 4; ++j)
          acc[i][j] = __builtin_amdgcn_mfma_f32_16x16x32_bf16(af[i], bfr[j], acc[i][j], 0, 0, 0);
    }
    __syncthreads();
  }

  float bvals[4];
  for (int j = 0; j < 4; ++j) bvals[j] = bias[bn + wn + j * 16 + l15];

  if constexpr (EPI == EPI_QKV) {
    const int cn = bn + wn;            // 64-aligned; wave covers exactly one head section
    const int sec = cn >> 10;          // 0=q, 1=k, 2=v
    if (sec == 2) {
      // V: write transposed into vtb[(b*16+h)*64 + d][t]
      const int b = bm >> 11;
      const int hh = (cn & 1023) >> 6;
      for (int i = 0; i < 4; ++i) {
        const int t0 = (bm + wm + i * 16 + quad * 4) & 2047;
        for (int j = 0; j < 4; ++j) {
          const int d = j * 16 + l15;
          u16x4 o;
          for (int r = 0; r < 4; ++r) o[r] = f2bf(acc[i][j][r] + bvals[j]);
          *(u16x4*)(vout + ((size_t)((b * 16 + hh) * 64 + d)) * 2048 + t0) = o;
        }
      }
    } else {
      const float qscale = (sec == 0) ? 0.18033688f : 1.0f;  // 0.125 * log2(e) folded into q
      unsigned short* qkvout = (unsigned short*)out;
      for (int i = 0; i < 4; ++i) {
        for (int r = 0; r < 4; ++r) {
          const int row = bm + wm + i * 16 + quad * 4 + r;
          const int t = row & 2047;
          for (int j = 0; j < 2; ++j) {
            const int d = j * 16 + l15;          // 0..31
            const float v1 = acc[i][j][r] + bvals[j];
            const float v2 = acc[i][j + 2][r] + bvals[j + 2];
            const float c = rc[t * 32 + d], s = rsn[t * 32 + d];
            const float o1 = (v1 * c - v2 * s) * qscale;
            const float o2 = (v2 * c + v1 * s) * qscale;
            const size_t base = (size_t)row * 3072 + cn + d;
            qkvout[base] = f2bf(o1);
            qkvout[base + 32] = f2bf(o2);
          }
        }
      }
    }
  } else {
    for (int i = 0; i < 4; ++i) {
      for (int r = 0; r < 4; ++r) {
        const size_t row = bm + wm + i * 16 + quad * 4 + r;
        for (int j = 0; j < 4; ++j) {
          const size_t col = bn + wn + j * 16 + l15;
          const float v = acc[i][j][r] + bvals[j];
          const size_t idx = row * (size_t)N + col;
          if constexpr (EPI == EPI_ATTNO) {
            ((float*)out)[idx] = resid[idx] + v;
          } else if constexpr (EPI == EPI_GELU) {
            const float gl = 0.5f * v * (1.0f + erff(v * 0.70710678118f));
            ((unsigned short*)out)[idx] = f2bf(gl);
          } else {  // EPI_FINAL
            ((float*)out)[idx] = resid[idx] + v;
          }
        }
      }
    }
  }
}

// ------------- Flash attention v7: 256 q-rows/block, wave owns 64q (2 groups) x 64kk -------
// r4 post-mortem: no pipe >45% busy -> sync/dependency-bound. Doubling q per staged
// K/V tile halves LDS frag reads, staging traffic, barriers and loop overhead per
// unit of work. kf[] read once and reused by both q-groups' QK; vf read once and
// feeds both q-groups' PV. z16 hoisted so accS init is MFMA(C=z16), not 16 movs.
__global__ __launch_bounds__(256, 2) void attn_kernel(
    const unsigned short* __restrict__ qkv,
    const unsigned short* __restrict__ vt,
    unsigned short* __restrict__ outb)
{
  __shared__ unsigned short Ks[2][4096] __attribute__((aligned(16)));  // 64x64 bf16 dbuf (16KB)
  __shared__ unsigned short Vs[2][4096] __attribute__((aligned(16)));  // Vt 64d x 64t dbuf (16KB)
  __shared__ float Sred[256];

  const int tid = threadIdx.x;
  const int lane = tid & 63, wave = tid >> 6;
  const int l31 = lane & 31, hl = lane >> 5;
  const int bh = blockIdx.y, b = bh >> 4, h = bh & 15;
  const int q0 = blockIdx.x * 256;
  const int qsub = wave * 64;

  // Q B-operand frags for both 32-q groups; q pre-scaled by log2e/8 in QKV epilogue
  bf16x8 qf[2][4];
  for (int qg = 0; qg < 2; ++qg) {
    const unsigned short* qp = qkv + (size_t)(b * 2048 + q0 + qsub + qg * 32 + l31) * 3072 + h * 64 + hl * 8;
    for (int kc = 0; kc < 4; ++kc) qf[qg][kc] = *(const bf16x8*)(qp + kc * 16);
  }

  // Staging gather addresses (swizzle folded into global address); 512 slots per matrix
  const int s0 = wave * 128 + lane, s1 = s0 + 64;
  const int r0 = s0 >> 3, c0 = (lane & 7) ^ (r0 & 7);
  const int r1 = s1 >> 3, c1 = (lane & 7) ^ (r1 & 7);
  const unsigned short* kbase = qkv + (size_t)(b * 2048) * 3072 + 1024 + h * 64;
  const unsigned short* ks0 = kbase + (size_t)r0 * 3072 + c0 * 8;
  const unsigned short* ks1 = kbase + (size_t)r1 * 3072 + c1 * 8;
  const unsigned short* vbase = vt + (size_t)bh * 64 * 2048;
  const unsigned short* vs0 = vbase + (size_t)r0 * 2048 + c0 * 8;
  const unsigned short* vs1 = vbase + (size_t)r1 * 2048 + c1 * 8;
  unsigned short* kd[2] = { Ks[0] + wave * 1024, Ks[1] + wave * 1024 };
  unsigned short* vd[2] = { Vs[0] + wave * 1024, Vs[1] + wave * 1024 };

  // Fragment slot offsets (ushort units). slot(row,ch) = row*8 + (ch ^ (row&7))
  int offK[2][4], offV[2][4];
  for (int g = 0; g < 2; ++g)
    for (int kc = 0; kc < 4; ++kc) {
      const int rk = g * 32 + l31;
      offK[g][kc] = (rk * 8 + ((2 * kc + hl) ^ (rk & 7))) * 8;
    }
  for (int dn = 0; dn < 2; ++dn)
    for (int t = 0; t < 4; ++t) {
      const int rv = dn * 32 + l31;
      offV[dn][t] = (rv * 8 + ((2 * t + hl) ^ (rv & 7))) * 8;
    }

  f32x16 accO[2][2];           // [qg][dn]
  for (int qg = 0; qg < 2; ++qg)
    for (int dn = 0; dn < 2; ++dn)
      for (int i = 0; i < 16; ++i) accO[qg][dn][i] = 0.f;
  float rsum[2] = {0.f, 0.f};

  f32x16 z16;
  for (int i = 0; i < 16; ++i) z16[i] = 0.f;

  // Prologue: stage tile 0 into buf 0 (drained by first loop barrier)
  async_cp16(ks0, kd[0]);
  async_cp16(ks1, kd[0] + 512);
  async_cp16(vs0, vd[0]);
  async_cp16(vs1, vd[0] + 512);

  for (int kt = 0; kt < 32; ++kt) {
    const int cur = kt & 1, nxt = cur ^ 1;
    __syncthreads();   // drains staging into cur; all waves done reading buf nxt (prev tile)
    if (kt < 31) {
      const size_t ko = (size_t)(kt + 1) * 64 * 3072;
      const int vo = (kt + 1) * 64;
      async_cp16(ks0 + ko, kd[nxt]);
      async_cp16(ks1 + ko, kd[nxt] + 512);
      async_cp16(vs0 + vo, vd[nxt]);
      async_cp16(vs1 + vo, vd[nxt] + 512);
    }
    for (int g = 0; g < 2; ++g) {
      // K-frags once, reused by both q-groups
      bf16x8 kf[4];
      for (int kc = 0; kc < 4; ++kc) kf[kc] = *(const bf16x8*)(Ks[cur] + offK[g][kc]);
      bf16x8 pfr[2][2];          // [qg][c]
      for (int qg = 0; qg < 2; ++qg) {
        // S^T = K Q^T: C cols = q (l31), rows = kk local
        __builtin_amdgcn_s_setprio(1);
        f32x16 accS = __builtin_amdgcn_mfma_f32_32x32x16_bf16(kf[0], qf[qg][0], z16, 0, 0, 0);
        for (int kc = 1; kc < 4; ++kc)
          accS = __builtin_amdgcn_mfma_f32_32x32x16_bf16(kf[kc], qf[qg][kc], accS, 0, 0, 0);
        __builtin_amdgcn_s_setprio(0);
        float p[16];
        for (int i = 0; i < 16; ++i) {
          p[i] = __builtin_amdgcn_exp2f(accS[i]);
          rsum[qg] += p[i];
        }
        // A-frag assembly via v_permlane32_swap_b32 (one swap fills both halves)
        for (int c = 0; c < 2; ++c) {
          const unsigned int xlo0 = pk2(p[8 * c + 0], p[8 * c + 1]);
          const unsigned int xlo1 = pk2(p[8 * c + 2], p[8 * c + 3]);
          const unsigned int xhi0 = pk2(p[8 * c + 4], p[8 * c + 5]);
          const unsigned int xhi1 = pk2(p[8 * c + 6], p[8 * c + 7]);
          const auto sw0 = __builtin_amdgcn_permlane32_swap(xlo0, xhi0, false, false);
          const auto sw1 = __builtin_amdgcn_permlane32_swap(xlo1, xhi1, false, false);
          u32x4 w;
          w[0] = sw0[0];
          w[1] = sw1[0];
          w[2] = sw0[1];
          w[3] = sw1[1];
          pfr[qg][c] = __builtin_bit_cast(bf16x8, w);
        }
      }
      // PV: vf read once per (c,dn), feeds both q-groups
      for (int c = 0; c < 2; ++c) {
        const int t = 2 * g + c;
        __builtin_amdgcn_s_setprio(1);
        for (int dn = 0; dn < 2; ++dn) {
          const bf16x8 vf = *(const bf16x8*)(Vs[cur] + offV[dn][t]);
          accO[0][dn] = __builtin_amdgcn_mfma_f32_32x32x16_bf16(pfr[0][c], vf, accO[0][dn], 0, 0, 0);
          accO[1][dn] = __builtin_amdgcn_mfma_f32_32x32x16_bf16(pfr[1][c], vf, accO[1][dn], 0, 0, 0);
        }
        __builtin_amdgcn_s_setprio(0);
      }
    }
  }

  // Row-sum broadcast: lane holds sum for q=qsub+qg*32+l31 (combine hl halves)
  for (int qg = 0; qg < 2; ++qg) {
    const float rs2 = rsum[qg] + __shfl_xor(rsum[qg], 32);
    if (hl == 0) Sred[qsub + qg * 32 + l31] = rs2;
  }
  __syncthreads();
  for (int qg = 0; qg < 2; ++qg)
    for (int reg = 0; reg < 16; ++reg) {
      const int rq = qsub + qg * 32 + (reg & 3) + 8 * (reg >> 2) + 4 * hl;
      const float inv = 1.0f / Sred[rq];
      const size_t row = (size_t)(b * 2048 + q0 + rq);
      for (int dn = 0; dn < 2; ++dn)
        outb[row * 1024 + h * 64 + dn * 32 + l31] = f2bf(accO[qg][dn][reg] * inv);
    }
}

extern "C" void kernel_launch(void* const* d_in, const int* in_sizes, int n_in,
                              void* d_out, int out_size, void* d_ws, size_t ws_size,
                              hipStream_t stream)
{
  const float* x        = (const float*)d_in[0];
  const float* rope_cos = (const float*)d_in[1];
  const float* rope_sin = (const float*)d_in[2];
  const float* ln1_g    = (const float*)d_in[3];
  const float* ln1_b    = (const float*)d_in[4];
  const float* Wqkv     = (const float*)d_in[5];
  const float* bqkv     = (const float*)d_in[6];
  const float* Wo       = (const float*)d_in[7];
  const float* bo       = (const float*)d_in[8];
  const float* ln2_g    = (const float*)d_in[9];
  const float* ln2_b    = (const float*)d_in[10];
  const float* W1       = (const float*)d_in[11];
  const float* b1       = (const float*)d_in[12];
  const float* W2       = (const float*)d_in[13];
  const float* b2       = (const float*)d_in[14];
  float* outp = (float*)d_out;

  char* ws = (char*)d_ws;
  size_t off = 0;
  auto alloc = [&](size_t bytes) -> void* {
    void* p = ws + off;
    off += (bytes + 255) & ~(size_t)255;
    return p;
  };
  unsigned short* h1    = (unsigned short*)alloc(8192ull * 1024 * 2);  // LN1 out; later reused as attn out
  unsigned short* wqkvT = (unsigned short*)alloc(3072ull * 1024 * 2);
  unsigned short* woT   = (unsigned short*)alloc(1024ull * 1024 * 2);
  unsigned short* w1T   = (unsigned short*)alloc(4096ull * 1024 * 2);
  unsigned short* w2T   = (unsigned short*)alloc(1024ull * 4096 * 2);
  unsigned short* qkv   = (unsigned short*)alloc(8192ull * 3072 * 2);
  unsigned short* vtb   = (unsigned short*)alloc(64ull * 64 * 2048 * 2);
  unsigned short* h2    = (unsigned short*)alloc(8192ull * 1024 * 2);
  unsigned short* ffb   = (unsigned short*)alloc(8192ull * 4096 * 2);

  wtrans_kernel<<<dim3(96, 32), 256, 0, stream>>>(Wqkv, wqkvT, 1024, 3072);
  wtrans_kernel<<<dim3(32, 32), 256, 0, stream>>>(Wo, woT, 1024, 1024);
  wtrans_kernel<<<dim3(128, 32), 256, 0, stream>>>(W1, w1T, 1024, 4096);
  wtrans_kernel<<<dim3(32, 128), 256, 0, stream>>>(W2, w2T, 4096, 1024);

  ln_kernel<<<8192, 256, 0, stream>>>(x, ln1_g, ln1_b, h1);
  gemm_bt<EPI_QKV><<<dim3(64, 24), 256, 0, stream>>>(h1, wqkvT, bqkv, nullptr, qkv,
                                                     8192, 3072, 1024, rope_cos, rope_sin, vtb);
  attn_kernel<<<dim3(8, 64), 256, 0, stream>>>(qkv, vtb, h1);
  gemm_bt<EPI_ATTNO><<<dim3(64, 8), 256, 0, stream>>>(h1, woT, bo, x, d_out,
                                                      8192, 1024, 1024, nullptr, nullptr, nullptr);
  ln_kernel<<<8192, 256, 0, stream>>>(outp, ln2_g, ln2_b, h2);
  gemm_bt<EPI_GELU><<<dim3(64, 32), 256, 0, stream>>>(h2, w1T, b1, nullptr, ffb,
                                                      8192, 4096, 1024, nullptr, nullptr, nullptr);
  gemm_bt<EPI_FINAL><<<dim3(64, 8), 256, 0, stream>>>(ffb, w2T, b2, outp, d_out,
                                                      8192, 1024, 4096, nullptr, nullptr, nullptr);
}

// Round 6
// 496.744 us; speedup vs baseline: 1.0353x; 1.0353x over previous
//
#include <hip/hip_runtime.h>
#include <hip/hip_bf16.h>
#include <math.h>

typedef __bf16 bf16x8 __attribute__((ext_vector_type(8)));
typedef float f32x4 __attribute__((ext_vector_type(4)));
typedef float f32x16 __attribute__((ext_vector_type(16)));
typedef unsigned short u16x8 __attribute__((ext_vector_type(8)));
typedef unsigned short u16x4 __attribute__((ext_vector_type(4)));
typedef unsigned int u32x4 __attribute__((ext_vector_type(4)));

#define DEV __device__ __forceinline__

DEV unsigned short f2bf(float f) { __bf16 h = (__bf16)f; return __builtin_bit_cast(unsigned short, h); }
DEV float bf2f(unsigned short u) { __bf16 h = __builtin_bit_cast(__bf16, u); return (float)h; }
DEV unsigned int pk2(float a, float b) {
  return (unsigned int)f2bf(a) | ((unsigned int)f2bf(b) << 16);
}

DEV void async_cp16(const void* g, void* l) {
  __builtin_amdgcn_global_load_lds((const __attribute__((address_space(1))) void*)g,
                                   (__attribute__((address_space(3))) void*)l, 16, 0, 0);
}

// SESSION NOTES:
// r1-3: 256x256 8-phase gemm abandoned — acc home stayed in scratch (WRITE_SIZE
//   327.7MB invariant, MfmaUtil 17%) across builtin/launch_bounds/asm-"+a" variants.
//   Do not retry without .s diagnostics.
// r4: attn SQ_LDS_BANK_CONFLICT == 4 per ds_read_b128 exactly — inherent b128 cost,
//   not a swizzle bug. Attn dependency/sync-bound, no pipe >45%.
// r5: attn QBLK=256 (2 q-groups/wave) halved conflicts+VALU as predicted but NEUTRAL
//   on time (93.3->94.0): latency-bound, lost TLP (occ 32->17%) ate the reuse gain.
//   Reverted to r4 attn. Sum-of-dispatches ~370-400us vs total ~500us => ~100us of
//   launch gaps across 11 dispatches -> this round fuses prep work: 11 -> 7 launches.

// ---------------- Fused prep: 4 weight transposes + LN1, segmented 1-D grid ----------------
// Segments: [0,3072) Wqkv^T, [3072,4096) Wo^T, [4096,8192) W1^T, [8192,12288) W2^T,
// [12288,20480) LN1 rows. All independent; all must finish before the QKV GEMM.
__global__ __launch_bounds__(256) void prep_kernel(
    const float* __restrict__ Wqkv, unsigned short* __restrict__ wqkvT,
    const float* __restrict__ Wo,   unsigned short* __restrict__ woT,
    const float* __restrict__ W1,   unsigned short* __restrict__ w1T,
    const float* __restrict__ W2,   unsigned short* __restrict__ w2T,
    const float* __restrict__ x, const float* __restrict__ g, const float* __restrict__ b,
    unsigned short* __restrict__ h1)
{
  const int id = blockIdx.x;
  const int tid = threadIdx.x;
  if (id < 12288) {
    // ---- weight transpose + fp32->bf16: out[N][K] = in[K][N], 32x32 tile ----
    const float* in; unsigned short* out; int K, N, bx, by;
    if (id < 3072)      { in = Wqkv; out = wqkvT; K = 1024; N = 3072; bx = id % 96;  by = id / 96; }
    else if (id < 4096) { const int t = id - 3072; in = Wo; out = woT; K = 1024; N = 1024; bx = t % 32;  by = t / 32; }
    else if (id < 8192) { const int t = id - 4096; in = W1; out = w1T; K = 1024; N = 4096; bx = t % 128; by = t / 128; }
    else                { const int t = id - 8192; in = W2; out = w2T; K = 4096; N = 1024; bx = t % 32;  by = t / 32; }
    __shared__ float tile[32][33];
    const int n0 = bx * 32, k0 = by * 32;
    const int r = tid >> 5, c = tid & 31;
    for (int p = 0; p < 4; ++p)
      tile[r + p * 8][c] = in[(size_t)(k0 + r + p * 8) * N + n0 + c];
    __syncthreads();
    for (int p = 0; p < 4; ++p)
      out[(size_t)(n0 + r + p * 8) * K + k0 + c] = f2bf(tile[c][r + p * 8]);
  } else {
    // ---- LayerNorm1 row ----
    const int row = id - 12288;
    const float4 v = ((const float4*)(x + (size_t)row * 1024))[tid];
    float s  = v.x + v.y + v.z + v.w;
    float sq = v.x*v.x + v.y*v.y + v.z*v.z + v.w*v.w;
    for (int m = 1; m < 64; m <<= 1) { s += __shfl_xor(s, m); sq += __shfl_xor(sq, m); }
    __shared__ float red[8];
    const int wave = tid >> 6;
    if ((tid & 63) == 0) { red[wave] = s; red[4 + wave] = sq; }
    __syncthreads();
    s  = red[0] + red[1] + red[2] + red[3];
    sq = red[4] + red[5] + red[6] + red[7];
    const float mu = s * (1.0f / 1024.0f);
    const float var = sq * (1.0f / 1024.0f) - mu * mu;
    const float rs = rsqrtf(var + 1e-5f);
    const float4 gv = ((const float4*)g)[tid];
    const float4 bv = ((const float4*)b)[tid];
    u16x4 o;
    o[0] = f2bf((v.x - mu) * rs * gv.x + bv.x);
    o[1] = f2bf((v.y - mu) * rs * gv.y + bv.y);
    o[2] = f2bf((v.z - mu) * rs * gv.z + bv.z);
    o[3] = f2bf((v.w - mu) * rs * gv.w + bv.w);
    *(u16x4*)(h1 + (size_t)row * 1024 + tid * 4) = o;
  }
}

// ---------------- LayerNorm: one block per row, D=1024 (used for LN2) ----------------
__global__ __launch_bounds__(256) void ln_kernel(const float* __restrict__ in,
    const float* __restrict__ g, const float* __restrict__ b,
    unsigned short* __restrict__ out)
{
  const int row = blockIdx.x;
  const int tid = threadIdx.x;
  const float4 v = ((const float4*)(in + (size_t)row * 1024))[tid];
  float s  = v.x + v.y + v.z + v.w;
  float sq = v.x*v.x + v.y*v.y + v.z*v.z + v.w*v.w;
  for (int m = 1; m < 64; m <<= 1) { s += __shfl_xor(s, m); sq += __shfl_xor(sq, m); }
  __shared__ float red[8];
  const int wave = tid >> 6;
  if ((tid & 63) == 0) { red[wave] = s; red[4 + wave] = sq; }
  __syncthreads();
  s  = red[0] + red[1] + red[2] + red[3];
  sq = red[4] + red[5] + red[6] + red[7];
  const float mu = s * (1.0f / 1024.0f);
  const float var = sq * (1.0f / 1024.0f) - mu * mu;
  const float rs = rsqrtf(var + 1e-5f);
  const float4 gv = ((const float4*)g)[tid];
  const float4 bv = ((const float4*)b)[tid];
  u16x4 o;
  o[0] = f2bf((v.x - mu) * rs * gv.x + bv.x);
  o[1] = f2bf((v.y - mu) * rs * gv.y + bv.y);
  o[2] = f2bf((v.z - mu) * rs * gv.z + bv.z);
  o[3] = f2bf((v.w - mu) * rs * gv.w + bv.w);
  *(u16x4*)(out + (size_t)row * 1024 + tid * 4) = o;
}

// ------------- bf16 GEMM, BK=64: C[M,N] = A[M,K] * Bt[N,K]^T + epilogue -------------
enum { EPI_QKV = 0, EPI_ATTNO = 1, EPI_GELU = 2, EPI_FINAL = 3 };

template <int EPI>
__global__ __launch_bounds__(256, 3) void gemm_bt(
    const unsigned short* __restrict__ A,
    const unsigned short* __restrict__ Bt,
    const float* __restrict__ bias,
    const float* __restrict__ resid,
    void* __restrict__ out,
    int M, int N, int K,
    const float* __restrict__ rc, const float* __restrict__ rsn,
    unsigned short* __restrict__ vout)
{
  __shared__ unsigned short lA[8192] __attribute__((aligned(16)));  // 128x64 bf16, swizzled slots
  __shared__ unsigned short lB[8192] __attribute__((aligned(16)));
  const int tid = threadIdx.x;
  const int lane = tid & 63, wave = tid >> 6;
  const int l15 = lane & 15, quad = lane >> 4;
  const int bm = blockIdx.x * 128, bn = blockIdx.y * 128;   // XCD-aware ordering
  const int wm = (wave & 1) * 64, wn = (wave >> 1) * 64;

  const unsigned short* ga[4]; const unsigned short* gb[4];
  unsigned short* la_dst[4]; unsigned short* lb_dst[4];
  for (int it = 0; it < 4; ++it) {
    const int s = it * 256 + tid;
    const int row = s >> 3;
    const int ch = (s & 7) ^ (row & 7);
    ga[it] = A  + (size_t)(bm + row) * K + ch * 8;
    gb[it] = Bt + (size_t)(bn + row) * K + ch * 8;
    const int base = (it * 256 + wave * 64) * 8;   // wave-uniform LDS base (ushort units)
    la_dst[it] = lA + base;
    lb_dst[it] = lB + base;
  }
  int offA[2][4], offB[2][4];
  for (int ks = 0; ks < 2; ++ks)
    for (int i = 0; i < 4; ++i) {
      int row = wm + i * 16 + l15;
      offA[ks][i] = (row * 8 + ((ks * 4 + quad) ^ (row & 7))) * 8;
      row = wn + i * 16 + l15;
      offB[ks][i] = (row * 8 + ((ks * 4 + quad) ^ (row & 7))) * 8;
    }

  f32x4 acc[4][4];
  for (int i = 0; i < 4; ++i)
    for (int j = 0; j < 4; ++j)
      acc[i][j] = f32x4{0.f, 0.f, 0.f, 0.f};

  for (int k0 = 0; k0 < K; k0 += 64) {
    for (int it = 0; it < 4; ++it) async_cp16(ga[it], la_dst[it]);
    for (int it = 0; it < 4; ++it) async_cp16(gb[it], lb_dst[it]);
    for (int it = 0; it < 4; ++it) { ga[it] += 64; gb[it] += 64; }
    __syncthreads();
    for (int ks = 0; ks < 2; ++ks) {
      bf16x8 af[4], bfr[4];
      for (int i = 0; i < 4; ++i) af[i]  = *(const bf16x8*)(lA + offA[ks][i]);
      for (int j = 0; j < 4; ++j) bfr[j] = *(const bf16x8*)(lB + offB[ks][j]);
      for (int i = 0; i < 4; ++i)
        for (int j = 0; j < 4; ++j)
          acc[i][j] = __builtin_amdgcn_mfma_f32_16x16x32_bf16(af[i], bfr[j], acc[i][j], 0, 0, 0);
    }
    __syncthreads();
  }

  float bvals[4];
  for (int j = 0; j < 4; ++j) bvals[j] = bias[bn + wn + j * 16 + l15];

  if constexpr (EPI == EPI_QKV) {
    const int cn = bn + wn;            // 64-aligned; wave covers exactly one head section
    const int sec = cn >> 10;          // 0=q, 1=k, 2=v
    if (sec == 2) {
      // V: write transposed into vtb[(b*16+h)*64 + d][t]
      const int b = bm >> 11;
      const int hh = (cn & 1023) >> 6;
      for (int i = 0; i < 4; ++i) {
        const int t0 = (bm + wm + i * 16 + quad * 4) & 2047;
        for (int j = 0; j < 4; ++j) {
          const int d = j * 16 + l15;
          u16x4 o;
          for (int r = 0; r < 4; ++r) o[r] = f2bf(acc[i][j][r] + bvals[j]);
          *(u16x4*)(vout + ((size_t)((b * 16 + hh) * 64 + d)) * 2048 + t0) = o;
        }
      }
    } else {
      const float qscale = (sec == 0) ? 0.18033688f : 1.0f;  // 0.125 * log2(e) folded into q
      unsigned short* qkvout = (unsigned short*)out;
      for (int i = 0; i < 4; ++i) {
        for (int r = 0; r < 4; ++r) {
          const int row = bm + wm + i * 16 + quad * 4 + r;
          const int t = row & 2047;
          for (int j = 0; j < 2; ++j) {
            const int d = j * 16 + l15;          // 0..31
            const float v1 = acc[i][j][r] + bvals[j];
            const float v2 = acc[i][j + 2][r] + bvals[j + 2];
            const float c = rc[t * 32 + d], s = rsn[t * 32 + d];
            const float o1 = (v1 * c - v2 * s) * qscale;
            const float o2 = (v2 * c + v1 * s) * qscale;
            const size_t base = (size_t)row * 3072 + cn + d;
            qkvout[base] = f2bf(o1);
            qkvout[base + 32] = f2bf(o2);
          }
        }
      }
    }
  } else {
    for (int i = 0; i < 4; ++i) {
      for (int r = 0; r < 4; ++r) {
        const size_t row = bm + wm + i * 16 + quad * 4 + r;
        for (int j = 0; j < 4; ++j) {
          const size_t col = bn + wn + j * 16 + l15;
          const float v = acc[i][j][r] + bvals[j];
          const size_t idx = row * (size_t)N + col;
          if constexpr (EPI == EPI_ATTNO) {
            ((float*)out)[idx] = resid[idx] + v;
          } else if constexpr (EPI == EPI_GELU) {
            const float gl = 0.5f * v * (1.0f + erff(v * 0.70710678118f));
            ((unsigned short*)out)[idx] = f2bf(gl);
          } else {  // EPI_FINAL
            ((float*)out)[idx] = resid[idx] + v;
          }
        }
      }
    }
  }
}

// ------------- Flash attention (r4 version, best measured 93.3us): 128 q-rows/block -------
// S^T = mfma(A=K, B=Q) per 32-kk group; in-register P via permlane32_swap; setprio(1)
// around MFMA clusters (T5). r5's QBLK=256 reuse variant was neutral — reverted.
__global__ __launch_bounds__(256, 4) void attn_kernel(
    const unsigned short* __restrict__ qkv,
    const unsigned short* __restrict__ vt,
    unsigned short* __restrict__ outb)
{
  __shared__ unsigned short Ks[2][4096] __attribute__((aligned(16)));  // 64x64 bf16 dbuf (16KB)
  __shared__ unsigned short Vs[2][4096] __attribute__((aligned(16)));  // Vt 64d x 64t dbuf (16KB)
  __shared__ float Sred[128];

  const int tid = threadIdx.x;
  const int lane = tid & 63, wave = tid >> 6;
  const int l31 = lane & 31, hl = lane >> 5;
  const int bh = blockIdx.y, b = bh >> 4, h = bh & 15;
  const int q0 = blockIdx.x * 128;
  const int qsub = wave * 32;

  // Q B-operand frags, hoisted: B[n=qsub+l31][k=kc*16+hl*8+i]; q pre-scaled by log2e/8
  bf16x8 qf[4];
  {
    const unsigned short* qp = qkv + (size_t)(b * 2048 + q0 + qsub + l31) * 3072 + h * 64 + hl * 8;
    for (int kc = 0; kc < 4; ++kc) qf[kc] = *(const bf16x8*)(qp + kc * 16);
  }

  // Staging gather addresses (swizzle folded into global address); 512 slots per matrix
  const int s0 = wave * 128 + lane, s1 = s0 + 64;
  const int r0 = s0 >> 3, c0 = (lane & 7) ^ (r0 & 7);
  const int r1 = s1 >> 3, c1 = (lane & 7) ^ (r1 & 7);
  const unsigned short* kbase = qkv + (size_t)(b * 2048) * 3072 + 1024 + h * 64;
  const unsigned short* ks0 = kbase + (size_t)r0 * 3072 + c0 * 8;
  const unsigned short* ks1 = kbase + (size_t)r1 * 3072 + c1 * 8;
  const unsigned short* vbase = vt + (size_t)bh * 64 * 2048;
  const unsigned short* vs0 = vbase + (size_t)r0 * 2048 + c0 * 8;
  const unsigned short* vs1 = vbase + (size_t)r1 * 2048 + c1 * 8;
  unsigned short* kd[2] = { Ks[0] + wave * 1024, Ks[1] + wave * 1024 };
  unsigned short* vd[2] = { Vs[0] + wave * 1024, Vs[1] + wave * 1024 };

  // Fragment slot offsets (ushort units). slot(row,ch) = row*8 + (ch ^ (row&7))
  int offK[2][4], offV[2][4];
  for (int g = 0; g < 2; ++g)
    for (int kc = 0; kc < 4; ++kc) {
      const int rk = g * 32 + l31;
      offK[g][kc] = (rk * 8 + ((2 * kc + hl) ^ (rk & 7))) * 8;
    }
  for (int dn = 0; dn < 2; ++dn)
    for (int t = 0; t < 4; ++t) {
      const int rv = dn * 32 + l31;
      offV[dn][t] = (rv * 8 + ((2 * t + hl) ^ (rv & 7))) * 8;
    }

  f32x16 accO[2];
  for (int dn = 0; dn < 2; ++dn)
    for (int i = 0; i < 16; ++i) accO[dn][i] = 0.f;
  float rsum = 0.f;

  // Prologue: stage tile 0 into buf 0 (drained by first loop barrier)
  async_cp16(ks0, kd[0]);
  async_cp16(ks1, kd[0] + 512);
  async_cp16(vs0, vd[0]);
  async_cp16(vs1, vd[0] + 512);

  for (int kt = 0; kt < 32; ++kt) {
    const int cur = kt & 1, nxt = cur ^ 1;
    __syncthreads();   // drains staging into cur; all waves done reading buf nxt (prev tile)
    if (kt < 31) {
      const size_t ko = (size_t)(kt + 1) * 64 * 3072;
      const int vo = (kt + 1) * 64;
      async_cp16(ks0 + ko, kd[nxt]);
      async_cp16(ks1 + ko, kd[nxt] + 512);
      async_cp16(vs0 + vo, vd[nxt]);
      async_cp16(vs1 + vo, vd[nxt] + 512);
    }
    for (int g = 0; g < 2; ++g) {
      // S^T = K Q^T for kk-group g: C cols = q (l31), rows = kk local
      f32x16 accS;
      for (int i = 0; i < 16; ++i) accS[i] = 0.f;
      __builtin_amdgcn_s_setprio(1);
      for (int kc = 0; kc < 4; ++kc) {
        const bf16x8 kf = *(const bf16x8*)(Ks[cur] + offK[g][kc]);
        accS = __builtin_amdgcn_mfma_f32_32x32x16_bf16(kf, qf[kc], accS, 0, 0, 0);
      }
      __builtin_amdgcn_s_setprio(0);
      // p = 2^s via raw v_exp_f32; deferred row sums
      float p[16];
      for (int i = 0; i < 16; ++i) {
        p[i] = __builtin_amdgcn_exp2f(accS[i]);
        rsum += p[i];
      }
      // PV: A-frag assembly via v_permlane32_swap_b32 — one swap yields both output
      // words (own-half and cross-half), no LDS traffic, no lane-select cndmasks.
      for (int c = 0; c < 2; ++c) {
        const unsigned int xlo0 = pk2(p[8 * c + 0], p[8 * c + 1]);
        const unsigned int xlo1 = pk2(p[8 * c + 2], p[8 * c + 3]);
        const unsigned int xhi0 = pk2(p[8 * c + 4], p[8 * c + 5]);
        const unsigned int xhi1 = pk2(p[8 * c + 6], p[8 * c + 7]);
        const auto sw0 = __builtin_amdgcn_permlane32_swap(xlo0, xhi0, false, false);
        const auto sw1 = __builtin_amdgcn_permlane32_swap(xlo1, xhi1, false, false);
        u32x4 w;
        w[0] = sw0[0];   // hl=0: kk{0,1}   hl=1: kk{8,9}
        w[1] = sw1[0];   // hl=0: kk{2,3}   hl=1: kk{10,11}
        w[2] = sw0[1];   // hl=0: kk{4,5}   hl=1: kk{12,13}
        w[3] = sw1[1];   // hl=0: kk{6,7}   hl=1: kk{14,15}
        const bf16x8 pf = __builtin_bit_cast(bf16x8, w);
        const int t = 2 * g + c;
        __builtin_amdgcn_s_setprio(1);
        for (int dn = 0; dn < 2; ++dn) {
          const bf16x8 vf = *(const bf16x8*)(Vs[cur] + offV[dn][t]);
          accO[dn] = __builtin_amdgcn_mfma_f32_32x32x16_bf16(pf, vf, accO[dn], 0, 0, 0);
        }
        __builtin_amdgcn_s_setprio(0);
      }
    }
  }

  // Row-sum broadcast: lane holds sum for q=qsub+l31 (combine hl halves), redistribute via LDS
  {
    const float rs2 = rsum + __shfl_xor(rsum, 32);
    if (hl == 0) Sred[qsub + l31] = rs2;
  }
  __syncthreads();
  for (int reg = 0; reg < 16; ++reg) {
    const int rq = qsub + (reg & 3) + 8 * (reg >> 2) + 4 * hl;
    const float inv = 1.0f / Sred[rq];
    const size_t row = (size_t)(b * 2048 + q0 + rq);
    for (int dn = 0; dn < 2; ++dn)
      outb[row * 1024 + h * 64 + dn * 32 + l31] = f2bf(accO[dn][reg] * inv);
  }
}

extern "C" void kernel_launch(void* const* d_in, const int* in_sizes, int n_in,
                              void* d_out, int out_size, void* d_ws, size_t ws_size,
                              hipStream_t stream)
{
  const float* x        = (const float*)d_in[0];
  const float* rope_cos = (const float*)d_in[1];
  const float* rope_sin = (const float*)d_in[2];
  const float* ln1_g    = (const float*)d_in[3];
  const float* ln1_b    = (const float*)d_in[4];
  const float* Wqkv     = (const float*)d_in[5];
  const float* bqkv     = (const float*)d_in[6];
  const float* Wo       = (const float*)d_in[7];
  const float* bo       = (const float*)d_in[8];
  const float* ln2_g    = (const float*)d_in[9];
  const float* ln2_b    = (const float*)d_in[10];
  const float* W1       = (const float*)d_in[11];
  const float* b1       = (const float*)d_in[12];
  const float* W2       = (const float*)d_in[13];
  const float* b2       = (const float*)d_in[14];
  float* outp = (float*)d_out;

  char* ws = (char*)d_ws;
  size_t off = 0;
  auto alloc = [&](size_t bytes) -> void* {
    void* p = ws + off;
    off += (bytes + 255) & ~(size_t)255;
    return p;
  };
  unsigned short* h1    = (unsigned short*)alloc(8192ull * 1024 * 2);  // LN1 out; later reused as attn out
  unsigned short* wqkvT = (unsigned short*)alloc(3072ull * 1024 * 2);
  unsigned short* woT   = (unsigned short*)alloc(1024ull * 1024 * 2);
  unsigned short* w1T   = (unsigned short*)alloc(4096ull * 1024 * 2);
  unsigned short* w2T   = (unsigned short*)alloc(1024ull * 4096 * 2);
  unsigned short* qkv   = (unsigned short*)alloc(8192ull * 3072 * 2);
  unsigned short* vtb   = (unsigned short*)alloc(64ull * 64 * 2048 * 2);
  unsigned short* h2    = (unsigned short*)alloc(8192ull * 1024 * 2);
  unsigned short* ffb   = (unsigned short*)alloc(8192ull * 4096 * 2);

  // Fused prep: 4 weight transposes + LN1 (was 5 separate launches)
  prep_kernel<<<20480, 256, 0, stream>>>(Wqkv, wqkvT, Wo, woT, W1, w1T, W2, w2T,
                                         x, ln1_g, ln1_b, h1);
  gemm_bt<EPI_QKV><<<dim3(64, 24), 256, 0, stream>>>(h1, wqkvT, bqkv, nullptr, qkv,
                                                     8192, 3072, 1024, rope_cos, rope_sin, vtb);
  attn_kernel<<<dim3(16, 64), 256, 0, stream>>>(qkv, vtb, h1);
  gemm_bt<EPI_ATTNO><<<dim3(64, 8), 256, 0, stream>>>(h1, woT, bo, x, d_out,
                                                      8192, 1024, 1024, nullptr, nullptr, nullptr);
  ln_kernel<<<8192, 256, 0, stream>>>(outp, ln2_g, ln2_b, h2);
  gemm_bt<EPI_GELU><<<dim3(64, 32), 256, 0, stream>>>(h2, w1T, b1, nullptr, ffb,
                                                      8192, 4096, 1024, nullptr, nullptr, nullptr);
  gemm_bt<EPI_FINAL><<<dim3(64, 8), 256, 0, stream>>>(ffb, w2T, b2, outp, d_out,
                                                      8192, 1024, 4096, nullptr, nullptr, nullptr);
}

// Round 7
// 487.393 us; speedup vs baseline: 1.0552x; 1.0192x over previous
//
#include <hip/hip_runtime.h>
#include <hip/hip_bf16.h>
#include <math.h>

typedef __bf16 bf16x8 __attribute__((ext_vector_type(8)));
typedef float f32x4 __attribute__((ext_vector_type(4)));
typedef float f32x16 __attribute__((ext_vector_type(16)));
typedef unsigned short u16x8 __attribute__((ext_vector_type(8)));
typedef unsigned short u16x4 __attribute__((ext_vector_type(4)));
typedef unsigned int u32x4 __attribute__((ext_vector_type(4)));

#define DEV __device__ __forceinline__

DEV unsigned short f2bf(float f) { __bf16 h = (__bf16)f; return __builtin_bit_cast(unsigned short, h); }
DEV float bf2f(unsigned short u) { __bf16 h = __builtin_bit_cast(__bf16, u); return (float)h; }

// T12 recipe: packed f32->bf16 pair conversion, one VOP3 instead of cvt+cvt+shl+or.
DEV unsigned int cvtpk(float lo, float hi) {
  unsigned int r;
  asm("v_cvt_pk_bf16_f32 %0, %1, %2" : "=v"(r) : "v"(lo), "v"(hi));
  return r;
}

DEV void async_cp16(const void* g, void* l) {
  __builtin_amdgcn_global_load_lds((const __attribute__((address_space(1))) void*)g,
                                   (__attribute__((address_space(3))) void*)l, 16, 0, 0);
}

// SESSION NOTES:
// r1-3: 256x256 8-phase gemm abandoned — acc home stayed in scratch (WRITE_SIZE
//   327.7MB invariant, MfmaUtil 17%) across builtin/launch_bounds/asm-"+a" variants.
//   Do not retry without .s diagnostics.
// r4: attn SQ_LDS_BANK_CONFLICT == 4 per ds_read_b128 exactly — inherent b128 cost.
// r5: attn QBLK=256 reuse: counters improved as predicted, time NEUTRAL (latency/TLP
//   tradeoff). Reverted.
// r6: prep fusion (11->7 launches): NEUTRAL — launch gaps were not the missing time;
//   GEMM dispatches are slower than modeled. Kept (harmless).
// r7 (this): attn is VALU-bound (VALUBusy 61% vs MfmaUtil 31%; ~190 VALU ops vs 16
//   MFMA per kt per wave). Cuts: rsum via ones-MFMA (accRS shares accO's reg->q
//   mapping; kills 32 adds/kt + entire Sred reduction), cvt_pk packing, z16 accS init.

// ---------------- Fused prep: 4 weight transposes + LN1, segmented 1-D grid ----------------
__global__ __launch_bounds__(256) void prep_kernel(
    const float* __restrict__ Wqkv, unsigned short* __restrict__ wqkvT,
    const float* __restrict__ Wo,   unsigned short* __restrict__ woT,
    const float* __restrict__ W1,   unsigned short* __restrict__ w1T,
    const float* __restrict__ W2,   unsigned short* __restrict__ w2T,
    const float* __restrict__ x, const float* __restrict__ g, const float* __restrict__ b,
    unsigned short* __restrict__ h1)
{
  const int id = blockIdx.x;
  const int tid = threadIdx.x;
  if (id < 12288) {
    const float* in; unsigned short* out; int K, N, bx, by;
    if (id < 3072)      { in = Wqkv; out = wqkvT; K = 1024; N = 3072; bx = id % 96;  by = id / 96; }
    else if (id < 4096) { const int t = id - 3072; in = Wo; out = woT; K = 1024; N = 1024; bx = t % 32;  by = t / 32; }
    else if (id < 8192) { const int t = id - 4096; in = W1; out = w1T; K = 1024; N = 4096; bx = t % 128; by = t / 128; }
    else                { const int t = id - 8192; in = W2; out = w2T; K = 4096; N = 1024; bx = t % 32;  by = t / 32; }
    __shared__ float tile[32][33];
    const int n0 = bx * 32, k0 = by * 32;
    const int r = tid >> 5, c = tid & 31;
    for (int p = 0; p < 4; ++p)
      tile[r + p * 8][c] = in[(size_t)(k0 + r + p * 8) * N + n0 + c];
    __syncthreads();
    for (int p = 0; p < 4; ++p)
      out[(size_t)(n0 + r + p * 8) * K + k0 + c] = f2bf(tile[c][r + p * 8]);
  } else {
    const int row = id - 12288;
    const float4 v = ((const float4*)(x + (size_t)row * 1024))[tid];
    float s  = v.x + v.y + v.z + v.w;
    float sq = v.x*v.x + v.y*v.y + v.z*v.z + v.w*v.w;
    for (int m = 1; m < 64; m <<= 1) { s += __shfl_xor(s, m); sq += __shfl_xor(sq, m); }
    __shared__ float red[8];
    const int wave = tid >> 6;
    if ((tid & 63) == 0) { red[wave] = s; red[4 + wave] = sq; }
    __syncthreads();
    s  = red[0] + red[1] + red[2] + red[3];
    sq = red[4] + red[5] + red[6] + red[7];
    const float mu = s * (1.0f / 1024.0f);
    const float var = sq * (1.0f / 1024.0f) - mu * mu;
    const float rs = rsqrtf(var + 1e-5f);
    const float4 gv = ((const float4*)g)[tid];
    const float4 bv = ((const float4*)b)[tid];
    u16x4 o;
    o[0] = f2bf((v.x - mu) * rs * gv.x + bv.x);
    o[1] = f2bf((v.y - mu) * rs * gv.y + bv.y);
    o[2] = f2bf((v.z - mu) * rs * gv.z + bv.z);
    o[3] = f2bf((v.w - mu) * rs * gv.w + bv.w);
    *(u16x4*)(h1 + (size_t)row * 1024 + tid * 4) = o;
  }
}

// ---------------- LayerNorm: one block per row, D=1024 (used for LN2) ----------------
__global__ __launch_bounds__(256) void ln_kernel(const float* __restrict__ in,
    const float* __restrict__ g, const float* __restrict__ b,
    unsigned short* __restrict__ out)
{
  const int row = blockIdx.x;
  const int tid = threadIdx.x;
  const float4 v = ((const float4*)(in + (size_t)row * 1024))[tid];
  float s  = v.x + v.y + v.z + v.w;
  float sq = v.x*v.x + v.y*v.y + v.z*v.z + v.w*v.w;
  for (int m = 1; m < 64; m <<= 1) { s += __shfl_xor(s, m); sq += __shfl_xor(sq, m); }
  __shared__ float red[8];
  const int wave = tid >> 6;
  if ((tid & 63) == 0) { red[wave] = s; red[4 + wave] = sq; }
  __syncthreads();
  s  = red[0] + red[1] + red[2] + red[3];
  sq = red[4] + red[5] + red[6] + red[7];
  const float mu = s * (1.0f / 1024.0f);
  const float var = sq * (1.0f / 1024.0f) - mu * mu;
  const float rs = rsqrtf(var + 1e-5f);
  const float4 gv = ((const float4*)g)[tid];
  const float4 bv = ((const float4*)b)[tid];
  u16x4 o;
  o[0] = f2bf((v.x - mu) * rs * gv.x + bv.x);
  o[1] = f2bf((v.y - mu) * rs * gv.y + bv.y);
  o[2] = f2bf((v.z - mu) * rs * gv.z + bv.z);
  o[3] = f2bf((v.w - mu) * rs * gv.w + bv.w);
  *(u16x4*)(out + (size_t)row * 1024 + tid * 4) = o;
}

// ------------- bf16 GEMM, BK=64: C[M,N] = A[M,K] * Bt[N,K]^T + epilogue -------------
enum { EPI_QKV = 0, EPI_ATTNO = 1, EPI_GELU = 2, EPI_FINAL = 3 };

template <int EPI>
__global__ __launch_bounds__(256, 3) void gemm_bt(
    const unsigned short* __restrict__ A,
    const unsigned short* __restrict__ Bt,
    const float* __restrict__ bias,
    const float* __restrict__ resid,
    void* __restrict__ out,
    int M, int N, int K,
    const float* __restrict__ rc, const float* __restrict__ rsn,
    unsigned short* __restrict__ vout)
{
  __shared__ unsigned short lA[8192] __attribute__((aligned(16)));  // 128x64 bf16, swizzled slots
  __shared__ unsigned short lB[8192] __attribute__((aligned(16)));
  const int tid = threadIdx.x;
  const int lane = tid & 63, wave = tid >> 6;
  const int l15 = lane & 15, quad = lane >> 4;
  const int bm = blockIdx.x * 128, bn = blockIdx.y * 128;   // XCD-aware ordering
  const int wm = (wave & 1) * 64, wn = (wave >> 1) * 64;

  const unsigned short* ga[4]; const unsigned short* gb[4];
  unsigned short* la_dst[4]; unsigned short* lb_dst[4];
  for (int it = 0; it < 4; ++it) {
    const int s = it * 256 + tid;
    const int row = s >> 3;
    const int ch = (s & 7) ^ (row & 7);
    ga[it] = A  + (size_t)(bm + row) * K + ch * 8;
    gb[it] = Bt + (size_t)(bn + row) * K + ch * 8;
    const int base = (it * 256 + wave * 64) * 8;   // wave-uniform LDS base (ushort units)
    la_dst[it] = lA + base;
    lb_dst[it] = lB + base;
  }
  int offA[2][4], offB[2][4];
  for (int ks = 0; ks < 2; ++ks)
    for (int i = 0; i < 4; ++i) {
      int row = wm + i * 16 + l15;
      offA[ks][i] = (row * 8 + ((ks * 4 + quad) ^ (row & 7))) * 8;
      row = wn + i * 16 + l15;
      offB[ks][i] = (row * 8 + ((ks * 4 + quad) ^ (row & 7))) * 8;
    }

  f32x4 acc[4][4];
  for (int i = 0; i < 4; ++i)
    for (int j = 0; j < 4; ++j)
      acc[i][j] = f32x4{0.f, 0.f, 0.f, 0.f};

  for (int k0 = 0; k0 < K; k0 += 64) {
    for (int it = 0; it < 4; ++it) async_cp16(ga[it], la_dst[it]);
    for (int it = 0; it < 4; ++it) async_cp16(gb[it], lb_dst[it]);
    for (int it = 0; it < 4; ++it) { ga[it] += 64; gb[it] += 64; }
    __syncthreads();
    for (int ks = 0; ks < 2; ++ks) {
      bf16x8 af[4], bfr[4];
      for (int i = 0; i < 4; ++i) af[i]  = *(const bf16x8*)(lA + offA[ks][i]);
      for (int j = 0; j < 4; ++j) bfr[j] = *(const bf16x8*)(lB + offB[ks][j]);
      for (int i = 0; i < 4; ++i)
        for (int j = 0; j < 4; ++j)
          acc[i][j] = __builtin_amdgcn_mfma_f32_16x16x32_bf16(af[i], bfr[j], acc[i][j], 0, 0, 0);
    }
    __syncthreads();
  }

  float bvals[4];
  for (int j = 0; j < 4; ++j) bvals[j] = bias[bn + wn + j * 16 + l15];

  if constexpr (EPI == EPI_QKV) {
    const int cn = bn + wn;            // 64-aligned; wave covers exactly one head section
    const int sec = cn >> 10;          // 0=q, 1=k, 2=v
    if (sec == 2) {
      // V: write transposed into vtb[(b*16+h)*64 + d][t]
      const int b = bm >> 11;
      const int hh = (cn & 1023) >> 6;
      for (int i = 0; i < 4; ++i) {
        const int t0 = (bm + wm + i * 16 + quad * 4) & 2047;
        for (int j = 0; j < 4; ++j) {
          const int d = j * 16 + l15;
          u16x4 o;
          for (int r = 0; r < 4; ++r) o[r] = f2bf(acc[i][j][r] + bvals[j]);
          *(u16x4*)(vout + ((size_t)((b * 16 + hh) * 64 + d)) * 2048 + t0) = o;
        }
      }
    } else {
      const float qscale = (sec == 0) ? 0.18033688f : 1.0f;  // 0.125 * log2(e) folded into q
      unsigned short* qkvout = (unsigned short*)out;
      for (int i = 0; i < 4; ++i) {
        for (int r = 0; r < 4; ++r) {
          const int row = bm + wm + i * 16 + quad * 4 + r;
          const int t = row & 2047;
          for (int j = 0; j < 2; ++j) {
            const int d = j * 16 + l15;          // 0..31
            const float v1 = acc[i][j][r] + bvals[j];
            const float v2 = acc[i][j + 2][r] + bvals[j + 2];
            const float c = rc[t * 32 + d], s = rsn[t * 32 + d];
            const float o1 = (v1 * c - v2 * s) * qscale;
            const float o2 = (v2 * c + v1 * s) * qscale;
            const size_t base = (size_t)row * 3072 + cn + d;
            qkvout[base] = f2bf(o1);
            qkvout[base + 32] = f2bf(o2);
          }
        }
      }
    }
  } else {
    for (int i = 0; i < 4; ++i) {
      for (int r = 0; r < 4; ++r) {
        const size_t row = bm + wm + i * 16 + quad * 4 + r;
        for (int j = 0; j < 4; ++j) {
          const size_t col = bn + wn + j * 16 + l15;
          const float v = acc[i][j][r] + bvals[j];
          const size_t idx = row * (size_t)N + col;
          if constexpr (EPI == EPI_ATTNO) {
            ((float*)out)[idx] = resid[idx] + v;
          } else if constexpr (EPI == EPI_GELU) {
            const float gl = 0.5f * v * (1.0f + erff(v * 0.70710678118f));
            ((unsigned short*)out)[idx] = f2bf(gl);
          } else {  // EPI_FINAL
            ((float*)out)[idx] = resid[idx] + v;
          }
        }
      }
    }
  }
}

// ------------- Flash attention v8: r4 structure + VALU diet -------------
// VALU-bound (r6: VALUBusy 61%, MfmaUtil 31%, ~190 VALU vs 16 MFMA per kt/wave).
// Cuts: (1) row-sum via ones-B MFMA into accRS — shares accO's (reg,hl)->q mapping,
// so the epilogue divides per-register with NO cross-lane reduction (Sred/shfl/
// syncthreads removed); denominator sums the same bf16-rounded P as the numerator.
// (2) v_cvt_pk_bf16_f32 packing (T12). (3) accS init via MFMA(C=z16).
__global__ __launch_bounds__(256, 4) void attn_kernel(
    const unsigned short* __restrict__ qkv,
    const unsigned short* __restrict__ vt,
    unsigned short* __restrict__ outb)
{
  __shared__ unsigned short Ks[2][4096] __attribute__((aligned(16)));  // 64x64 bf16 dbuf (16KB)
  __shared__ unsigned short Vs[2][4096] __attribute__((aligned(16)));  // Vt 64d x 64t dbuf (16KB)

  const int tid = threadIdx.x;
  const int lane = tid & 63, wave = tid >> 6;
  const int l31 = lane & 31, hl = lane >> 5;
  const int bh = blockIdx.y, b = bh >> 4, h = bh & 15;
  const int q0 = blockIdx.x * 128;
  const int qsub = wave * 32;

  // Q B-operand frags, hoisted: B[n=qsub+l31][k=kc*16+hl*8+i]; q pre-scaled by log2e/8
  bf16x8 qf[4];
  {
    const unsigned short* qp = qkv + (size_t)(b * 2048 + q0 + qsub + l31) * 3072 + h * 64 + hl * 8;
    for (int kc = 0; kc < 4; ++kc) qf[kc] = *(const bf16x8*)(qp + kc * 16);
  }

  // Staging gather addresses (swizzle folded into global address); 512 slots per matrix
  const int s0 = wave * 128 + lane, s1 = s0 + 64;
  const int r0 = s0 >> 3, c0 = (lane & 7) ^ (r0 & 7);
  const int r1 = s1 >> 3, c1 = (lane & 7) ^ (r1 & 7);
  const unsigned short* kbase = qkv + (size_t)(b * 2048) * 3072 + 1024 + h * 64;
  const unsigned short* ks0 = kbase + (size_t)r0 * 3072 + c0 * 8;
  const unsigned short* ks1 = kbase + (size_t)r1 * 3072 + c1 * 8;
  const unsigned short* vbase = vt + (size_t)bh * 64 * 2048;
  const unsigned short* vs0 = vbase + (size_t)r0 * 2048 + c0 * 8;
  const unsigned short* vs1 = vbase + (size_t)r1 * 2048 + c1 * 8;
  unsigned short* kd[2] = { Ks[0] + wave * 1024, Ks[1] + wave * 1024 };
  unsigned short* vd[2] = { Vs[0] + wave * 1024, Vs[1] + wave * 1024 };

  // Fragment slot offsets (ushort units). slot(row,ch) = row*8 + (ch ^ (row&7))
  int offK[2][4], offV[2][4];
  for (int g = 0; g < 2; ++g)
    for (int kc = 0; kc < 4; ++kc) {
      const int rk = g * 32 + l31;
      offK[g][kc] = (rk * 8 + ((2 * kc + hl) ^ (rk & 7))) * 8;
    }
  for (int dn = 0; dn < 2; ++dn)
    for (int t = 0; t < 4; ++t) {
      const int rv = dn * 32 + l31;
      offV[dn][t] = (rv * 8 + ((2 * t + hl) ^ (rv & 7))) * 8;
    }

  f32x16 accO[2];
  f32x16 accRS;            // row-sum accumulator, same C layout as accO
  for (int dn = 0; dn < 2; ++dn)
    for (int i = 0; i < 16; ++i) accO[dn][i] = 0.f;
  for (int i = 0; i < 16; ++i) accRS[i] = 0.f;

  f32x16 z16;
  for (int i = 0; i < 16; ++i) z16[i] = 0.f;
  bf16x8 onesB;            // splat bf16 1.0 — layout-invariant B operand
  {
    u32x4 ob;
    for (int i = 0; i < 4; ++i) ob[i] = 0x3F803F80u;
    onesB = __builtin_bit_cast(bf16x8, ob);
  }

  // Prologue: stage tile 0 into buf 0 (drained by first loop barrier)
  async_cp16(ks0, kd[0]);
  async_cp16(ks1, kd[0] + 512);
  async_cp16(vs0, vd[0]);
  async_cp16(vs1, vd[0] + 512);

  for (int kt = 0; kt < 32; ++kt) {
    const int cur = kt & 1, nxt = cur ^ 1;
    __syncthreads();   // drains staging into cur; all waves done reading buf nxt (prev tile)
    if (kt < 31) {
      const size_t ko = (size_t)(kt + 1) * 64 * 3072;
      const int vo = (kt + 1) * 64;
      async_cp16(ks0 + ko, kd[nxt]);
      async_cp16(ks1 + ko, kd[nxt] + 512);
      async_cp16(vs0 + vo, vd[nxt]);
      async_cp16(vs1 + vo, vd[nxt] + 512);
    }
    for (int g = 0; g < 2; ++g) {
      // S^T = K Q^T for kk-group g: C cols = q (l31), rows = kk local
      f32x16 accS;
      __builtin_amdgcn_s_setprio(1);
      {
        const bf16x8 kf = *(const bf16x8*)(Ks[cur] + offK[g][0]);
        accS = __builtin_amdgcn_mfma_f32_32x32x16_bf16(kf, qf[0], z16, 0, 0, 0);
      }
      for (int kc = 1; kc < 4; ++kc) {
        const bf16x8 kf = *(const bf16x8*)(Ks[cur] + offK[g][kc]);
        accS = __builtin_amdgcn_mfma_f32_32x32x16_bf16(kf, qf[kc], accS, 0, 0, 0);
      }
      __builtin_amdgcn_s_setprio(0);
      // p = 2^s via raw v_exp_f32 (row sums come free via the ones-MFMA below)
      float p[16];
      for (int i = 0; i < 16; ++i) p[i] = __builtin_amdgcn_exp2f(accS[i]);
      // PV A-frag assembly: cvt_pk pairs + one permlane32_swap per word-pair
      for (int c = 0; c < 2; ++c) {
        const unsigned int xlo0 = cvtpk(p[8 * c + 0], p[8 * c + 1]);
        const unsigned int xlo1 = cvtpk(p[8 * c + 2], p[8 * c + 3]);
        const unsigned int xhi0 = cvtpk(p[8 * c + 4], p[8 * c + 5]);
        const unsigned int xhi1 = cvtpk(p[8 * c + 6], p[8 * c + 7]);
        const auto sw0 = __builtin_amdgcn_permlane32_swap(xlo0, xhi0, false, false);
        const auto sw1 = __builtin_amdgcn_permlane32_swap(xlo1, xhi1, false, false);
        u32x4 w;
        w[0] = sw0[0];   // hl=0: kk{0,1}   hl=1: kk{8,9}
        w[1] = sw1[0];   // hl=0: kk{2,3}   hl=1: kk{10,11}
        w[2] = sw0[1];   // hl=0: kk{4,5}   hl=1: kk{12,13}
        w[3] = sw1[1];   // hl=0: kk{6,7}   hl=1: kk{14,15}
        const bf16x8 pf = __builtin_bit_cast(bf16x8, w);
        const int t = 2 * g + c;
        __builtin_amdgcn_s_setprio(1);
        for (int dn = 0; dn < 2; ++dn) {
          const bf16x8 vf = *(const bf16x8*)(Vs[cur] + offV[dn][t]);
          accO[dn] = __builtin_amdgcn_mfma_f32_32x32x16_bf16(pf, vf, accO[dn], 0, 0, 0);
        }
        accRS = __builtin_amdgcn_mfma_f32_32x32x16_bf16(pf, onesB, accRS, 0, 0, 0);
        __builtin_amdgcn_s_setprio(0);
      }
    }
  }

  // Epilogue: accRS[reg] holds sum_k P[q][k] for the SAME q as accO[*][reg] — divide in place.
  for (int reg = 0; reg < 16; ++reg) {
    const float inv = 1.0f / accRS[reg];
    const int rq = qsub + (reg & 3) + 8 * (reg >> 2) + 4 * hl;
    const size_t row = (size_t)(b * 2048 + q0 + rq);
    for (int dn = 0; dn < 2; ++dn)
      outb[row * 1024 + h * 64 + dn * 32 + l31] = f2bf(accO[dn][reg] * inv);
  }
}

extern "C" void kernel_launch(void* const* d_in, const int* in_sizes, int n_in,
                              void* d_out, int out_size, void* d_ws, size_t ws_size,
                              hipStream_t stream)
{
  const float* x        = (const float*)d_in[0];
  const float* rope_cos = (const float*)d_in[1];
  const float* rope_sin = (const float*)d_in[2];
  const float* ln1_g    = (const float*)d_in[3];
  const float* ln1_b    = (const float*)d_in[4];
  const float* Wqkv     = (const float*)d_in[5];
  const float* bqkv     = (const float*)d_in[6];
  const float* Wo       = (const float*)d_in[7];
  const float* bo       = (const float*)d_in[8];
  const float* ln2_g    = (const float*)d_in[9];
  const float* ln2_b    = (const float*)d_in[10];
  const float* W1       = (const float*)d_in[11];
  const float* b1       = (const float*)d_in[12];
  const float* W2       = (const float*)d_in[13];
  const float* b2       = (const float*)d_in[14];
  float* outp = (float*)d_out;

  char* ws = (char*)d_ws;
  size_t off = 0;
  auto alloc = [&](size_t bytes) -> void* {
    void* p = ws + off;
    off += (bytes + 255) & ~(size_t)255;
    return p;
  };
  unsigned short* h1    = (unsigned short*)alloc(8192ull * 1024 * 2);  // LN1 out; later reused as attn out
  unsigned short* wqkvT = (unsigned short*)alloc(3072ull * 1024 * 2);
  unsigned short* woT   = (unsigned short*)alloc(1024ull * 1024 * 2);
  unsigned short* w1T   = (unsigned short*)alloc(4096ull * 1024 * 2);
  unsigned short* w2T   = (unsigned short*)alloc(1024ull * 4096 * 2);
  unsigned short* qkv   = (unsigned short*)alloc(8192ull * 3072 * 2);
  unsigned short* vtb   = (unsigned short*)alloc(64ull * 64 * 2048 * 2);
  unsigned short* h2    = (unsigned short*)alloc(8192ull * 1024 * 2);
  unsigned short* ffb   = (unsigned short*)alloc(8192ull * 4096 * 2);

  // Fused prep: 4 weight transposes + LN1
  prep_kernel<<<20480, 256, 0, stream>>>(Wqkv, wqkvT, Wo, woT, W1, w1T, W2, w2T,
                                         x, ln1_g, ln1_b, h1);
  gemm_bt<EPI_QKV><<<dim3(64, 24), 256, 0, stream>>>(h1, wqkvT, bqkv, nullptr, qkv,
                                                     8192, 3072, 1024, rope_cos, rope_sin, vtb);
  attn_kernel<<<dim3(16, 64), 256, 0, stream>>>(qkv, vtb, h1);
  gemm_bt<EPI_ATTNO><<<dim3(64, 8), 256, 0, stream>>>(h1, woT, bo, x, d_out,
                                                      8192, 1024, 1024, nullptr, nullptr, nullptr);
  ln_kernel<<<8192, 256, 0, stream>>>(outp, ln2_g, ln2_b, h2);
  gemm_bt<EPI_GELU><<<dim3(64, 32), 256, 0, stream>>>(h2, w1T, b1, nullptr, ffb,
                                                      8192, 4096, 1024, nullptr, nullptr, nullptr);
  gemm_bt<EPI_FINAL><<<dim3(64, 8), 256, 0, stream>>>(ffb, w2T, b2, outp, d_out,
                                                      8192, 1024, 4096, nullptr, nullptr, nullptr);
}